// Round 2
// baseline (142.682 us; speedup 1.0000x reference)
//
#include <hip/hip_runtime.h>

#define BATCH 524288

typedef __bf16 bf16x8 __attribute__((ext_vector_type(8)));
typedef __bf16 bf16x2 __attribute__((ext_vector_type(2)));
typedef float f32x4 __attribute__((ext_vector_type(4)));
typedef float f32x8 __attribute__((ext_vector_type(8)));
typedef float f32x2 __attribute__((ext_vector_type(2)));

// LDS layout (all fragment reads are lane-consecutive 16B chunks = conflict-free):
//   sA2  @     0: 16384 B  A2, chunk(kk, lane)=kk*1024+lane*16; lane(c,q) elems j ->
//                          A[n=2kk+(q>>1)][k_out=c][d=(q&1)*8+j]
//   sW1f @ 16384:  4096 B  W1 frags, chunk(t, q*16+c) for q<2; +32 B zero chunk @ 20480
//   sW2f @ 20512:  8192 B  W2 permuted frags (v9-verified), chunk(t2*4+s)*1024 + lane*16
//   sB2  @ 28704:   128 B  b2 f32 (broadcast float4 reads)
//   sXT  @ 28832:    64 B  x_target f32
//   hcw  @ 28896 + wave*2560 + t01*1280: 16 rows x 40 bf16 (packed-b32 writes = 2/bank free)
//
// v11: 1024-thread blocks (16 waves). Fixed 28.9 KB staging amortized over 1024 rows;
//      LDS/block = 69856 B -> exactly 2 blocks/CU -> 32 waves/CU (was 16). Grid = 512
//      blocks = 2/CU fully resident. Latency-bound fix: 8 waves/SIMD to hide LDS
//      round-trips + exp chains. Needs >64KB dyn-LDS attribute opt-in (gfx950 OK).
#define SW1 16384
#define SZC 20480
#define SW2 20512
#define SB2 28704
#define SXT 28832
#define SHC 28896
#define NWAVES 16
#define SMEM_BYTES (28896 + NWAVES * 2560)   // 69856 B -> 2 blocks/CU, 32 waves/CU

__device__ __forceinline__ f32x8 load8(const float* __restrict__ p) {
    float4 a = *(const float4*)p;
    float4 b = *(const float4*)(p + 4);
    f32x8 v = {a.x, a.y, a.z, a.w, b.x, b.y, b.z, b.w};
    return v;
}

__device__ __forceinline__ int pack2bf(float a, float b) {
    f32x2 v = {a, b};
    bf16x2 p = __builtin_convertvector(v, bf16x2);
    return __builtin_bit_cast(int, p);
}

__global__ __launch_bounds__(1024, 8) void andp_v11(
    const float* __restrict__ x_cur,
    const float* __restrict__ W1,
    const float* __restrict__ b1,
    const float* __restrict__ W2,
    const float* __restrict__ b2,
    const float* __restrict__ Bm,
    const float* __restrict__ Cm,
    const float* __restrict__ x_t,
    float* __restrict__ out)
{
    extern __shared__ char smem[];
    int* sA2i = (int*)smem;
    int* sW1i = (int*)(smem + SW1);
    int* sW2i = (int*)(smem + SW2);
    const int tid = threadIdx.x;

    // ---- stage A2 = Bm + Cm, lane-consecutive chunk order ----
#pragma unroll
    for (int i = 0; i < 4; ++i) {
        int o2 = tid + i * 1024;                // b32 index 0..4095
        int o  = o2 * 2;                        // elem (j even)
        int kk = o >> 9, qp = (o >> 7) & 3, k = (o >> 3) & 15, j = o & 7;
        int n = 2 * kk + (qp >> 1), d = (qp & 1) * 8 + j;
        int src = n * 256 + k * 16 + d;
        float2 bv = *(const float2*)(Bm + src);
        float2 cv = *(const float2*)(Cm + src);
        sA2i[o2] = pack2bf(bv.x + cv.x, bv.y + cv.y);
    }
    // ---- stage W1 frags, lane-consecutive chunk order; + zero chunk ----
    {
        int o2 = tid;                           // b32 index 0..1023 (one per thread)
        int o  = o2 * 2;                        // elem (j even)
        int t = o >> 8, qq = (o >> 7) & 1, cc = (o >> 3) & 15, j = o & 7;
        int src = (t * 16 + cc) * 16 + qq * 8 + j;
        float2 v = *(const float2*)(W1 + src);
        sW1i[o2] = pack2bf(v.x, v.y);
    }
    if (tid < 8) ((int*)(smem + SZC))[tid] = 0;
    // ---- stage W2 in permuted frag order (v9-verified) ----
#pragma unroll
    for (int i = 0; i < 2; ++i) {
        int o2 = tid + i * 1024;                // b32 index 0..2047
        int chunk = o2 >> 8, rem = o2 & 255;
        int ln = rem >> 2, j2 = rem & 3;
        int qq = ln >> 4, cc = ln & 15;
        int t2 = chunk >> 2, s = chunk & 3;
        int src = (t2 * 16 + cc) * 128 + s * 32 + 4 * qq + j2;
        sW2i[o2] = pack2bf(W2[src], W2[src + 16]);
    }
    if (tid < 32) ((float*)(smem + SB2))[tid] = b2[tid];
    if (tid < 16) ((float*)(smem + SXT))[tid] = x_t[tid];

    const int wave = tid >> 6, lane = tid & 63;
    const int c = lane & 15, q = lane >> 4;
    const int qh = q >> 1;                       // n parity for G3
    const int hh = (q & 1) * 8;                  // d-half this lane owns
    const int c4 = c * 4;

    const char* sW1f = smem + SW1;
    const int w1base = (q < 2) ? ((q * 16 + c) * 16) : (SZC - SW1);
    const int w1step = (q < 2) ? 512 : 0;
    const char* sW2f = smem + SW2 + lane * 16;   // + chunk*1024
    __bf16* hcw0 = (__bf16*)(smem + SHC + wave * 2560);
    __bf16* hcw1 = hcw0 + 640;
    const float* sB2f = (const float*)(smem + SB2);
    const float* sXTf = (const float*)(smem + SXT);

    float b1v[8];
#pragma unroll
    for (int t = 0; t < 8; ++t) b1v[t] = b1[t * 16 + c];

    __syncthreads();

    const int blk_row = blockIdx.x * 1024 + wave * 64;
    const f32x4 z4 = {0.f, 0.f, 0.f, 0.f};

#pragma unroll 1
    for (int p = 0; p < 2; ++p) {
        const int r0 = blk_row + p * 32;

        // ---- x from global -> bf16 A-frag only (dif reconstructed at G3) ----
        bf16x8 af[2];
#pragma unroll
        for (int t01 = 0; t01 < 2; ++t01) {
            f32x8 xv = load8(x_cur + (size_t)(r0 + t01 * 16 + c) * 16 + hh);
            af[t01] = __builtin_convertvector(xv, bf16x8);
        }

        // ---- fused G1/G2, t01-interleaved ----
        f32x4 acc2[2][2];
        acc2[0][0] = z4; acc2[0][1] = z4; acc2[1][0] = z4; acc2[1][1] = z4;
#pragma unroll
        for (int s = 0; s < 4; ++s) {
#pragma unroll
            for (int t01 = 0; t01 < 2; ++t01) {
                __bf16* hcw = t01 ? hcw1 : hcw0;
                bf16x8 w1a = *(const bf16x8*)(sW1f + w1base + (2 * s) * w1step);
                bf16x8 w1b = *(const bf16x8*)(sW1f + w1base + (2 * s + 1) * w1step);
                f32x4 a1a = __builtin_amdgcn_mfma_f32_16x16x32_bf16(af[t01], w1a, z4, 0, 0, 0);
                f32x4 a1b = __builtin_amdgcn_mfma_f32_16x16x32_bf16(af[t01], w1b, z4, 0, 0, 0);
#pragma unroll
                for (int r = 0; r < 4; ++r) {
                    float va = fmaxf(a1a[r] + b1v[2 * s], 0.f);
                    float vb = fmaxf(a1b[r] + b1v[2 * s + 1], 0.f);
                    *(int*)(hcw + (q * 4 + r) * 40 + 2 * c) = pack2bf(va, vb);
                }
            }
#pragma unroll
            for (int t01 = 0; t01 < 2; ++t01) {
                __bf16* hcw = t01 ? hcw1 : hcw0;
                bf16x8 hb = *(const bf16x8*)(hcw + c * 40 + q * 8);
                bf16x8 w20 = *(const bf16x8*)(sW2f + (0 * 4 + s) * 1024);
                bf16x8 w21 = *(const bf16x8*)(sW2f + (1 * 4 + s) * 1024);
                acc2[t01][0] = __builtin_amdgcn_mfma_f32_16x16x32_bf16(w20, hb, acc2[t01][0], 0, 0, 0);
                acc2[t01][1] = __builtin_amdgcn_mfma_f32_16x16x32_bf16(w21, hb, acc2[t01][1], 0, 0, 0);
            }
        }

        // ---- softmax (no max-sub; b2 from LDS broadcast reads) ----
        int wq[8];
        {
            f32x4 bq0 = *(const f32x4*)(sB2f + q * 4);
            f32x4 bq1 = *(const f32x4*)(sB2f + 16 + q * 4);
#pragma unroll
            for (int t01 = 0; t01 < 2; ++t01) {
                float e[8], sum = 0.f;
#pragma unroll
                for (int r = 0; r < 4; ++r) {
                    e[r]     = __expf(acc2[t01][0][r] + bq0[r]);
                    e[4 + r] = __expf(acc2[t01][1][r] + bq1[r]);
                    sum += e[r] + e[4 + r];
                }
                sum += __shfl_xor(sum, 16, 64);
                sum += __shfl_xor(sum, 32, 64);
                float inv = 1.0f / sum;
                if (t01 == 0) {
#pragma unroll
                    for (int i = 0; i < 8; ++i) wq[i] = pack2bf(e[i] * inv, 0.f);
                } else {
#pragma unroll
                    for (int i = 0; i < 8; ++i) wq[i] |= pack2bf(0.f, e[i] * inv);
                }
            }
        }

        // ---- reconstruct dif from af (bf16 x) + LDS x_target ----
        f32x8 dif[2];
        {
            f32x4 xta = *(const f32x4*)(sXTf + hh);
            f32x4 xtb = *(const f32x4*)(sXTf + hh + 4);
            f32x8 xtv = {xta[0], xta[1], xta[2], xta[3], xtb[0], xtb[1], xtb[2], xtb[3]};
            dif[0] = xtv - __builtin_convertvector(af[0], f32x8);
            dif[1] = xtv - __builtin_convertvector(af[1], f32x8);
        }

        // ---- G3 (v8-verified gate fetch; lane-consecutive A2 chunks) ----
        f32x4 acc3[2];
        acc3[0] = z4; acc3[1] = z4;
#pragma unroll
        for (int kk = 0; kk < 16; ++kk) {
            const int lo = (kk >> 3) * 4 + 2 * (kk & 1);
            const int bpi = c4 + ((kk >> 1) & 3) * 64;
            int bpA = __builtin_amdgcn_ds_bpermute(bpi, wq[lo]);      // n = 2kk
            int bpB = __builtin_amdgcn_ds_bpermute(bpi, wq[lo + 1]);  // n = 2kk+1
            int sel = qh ? bpB : bpA;                                  // n = 2kk+qh
            float w0 = __builtin_bit_cast(float, (unsigned)sel << 16);
            float w1 = __builtin_bit_cast(float, (unsigned)sel & 0xffff0000u);
            bf16x8 a2f = *(const bf16x8*)(smem + kk * 1024 + lane * 16);
            bf16x8 g0 = __builtin_convertvector(dif[0] * w0, bf16x8);
            bf16x8 g1 = __builtin_convertvector(dif[1] * w1, bf16x8);
            acc3[0] = __builtin_amdgcn_mfma_f32_16x16x32_bf16(a2f, g0, acc3[0], 0, 0, 0);
            acc3[1] = __builtin_amdgcn_mfma_f32_16x16x32_bf16(a2f, g1, acc3[1], 0, 0, 0);
        }

        // ---- store: D[m=k_out=q*4+r][n=row=c] -> float4 per tile ----
#pragma unroll
        for (int t01 = 0; t01 < 2; ++t01) {
            float4 st = make_float4(acc3[t01][0], acc3[t01][1], acc3[t01][2], acc3[t01][3]);
            *(float4*)(out + (size_t)(r0 + t01 * 16 + c) * 16 + q * 4) = st;
        }
    }
}

extern "C" void kernel_launch(void* const* d_in, const int* in_sizes, int n_in,
                              void* d_out, int out_size, void* d_ws, size_t ws_size,
                              hipStream_t stream) {
    const float* x_cur = (const float*)d_in[0];
    const float* W1    = (const float*)d_in[1];
    const float* b1    = (const float*)d_in[2];
    const float* W2    = (const float*)d_in[3];
    const float* b2    = (const float*)d_in[4];
    const float* Bm    = (const float*)d_in[5];
    const float* Cm    = (const float*)d_in[6];
    const float* x_t   = (const float*)d_in[7];
    float* out = (float*)d_out;

    // >64KB dynamic LDS needs explicit opt-in (one-time; not a stream op, graph-safe)
    static bool attr_set = false;
    if (!attr_set) {
        (void)hipFuncSetAttribute((const void*)andp_v11,
                                  hipFuncAttributeMaxDynamicSharedMemorySize,
                                  SMEM_BYTES);
        attr_set = true;
    }

    const int blocks = BATCH / 1024;   // 512 blocks x 1024 rows, exactly 2 blocks/CU
    andp_v11<<<blocks, 1024, SMEM_BYTES, stream>>>(
        x_cur, W1, b1, W2, b2, Bm, Cm, x_t, out);
}

// Round 3
// 128.155 us; speedup vs baseline: 1.1134x; 1.1134x over previous
//
#include <hip/hip_runtime.h>

#define BATCH 524288

typedef __bf16 bf16x8 __attribute__((ext_vector_type(8)));
typedef __bf16 bf16x2 __attribute__((ext_vector_type(2)));
typedef float f32x4 __attribute__((ext_vector_type(4)));
typedef float f32x8 __attribute__((ext_vector_type(8)));
typedef float f32x2 __attribute__((ext_vector_type(2)));

// LDS layout (all fragment reads are lane-consecutive 16B chunks = conflict-free):
//   sA2  @     0: 16384 B  A2, chunk(kk, lane)=kk*1024+lane*16; lane(c,q) elems j ->
//                          A[n=2kk+(q>>1)][k_out=c][d=(q&1)*8+j]
//   sW1f @ 16384:  4096 B  W1 frags, chunk(t, q*16+c) for q<2; +32 B zero chunk @ 20480
//   sW2f @ 20512:  8192 B  W2 permuted frags (v9-verified), chunk(t2*4+s)*1024 + lane*16
//   sB2  @ 28704:   128 B  b2 f32 (broadcast float4 reads)
//   sXT  @ 28832:    64 B  x_target f32
//   sB1  @ 28896:   512 B  b1 f32 (broadcast reads, replaces b1v[8] VGPR array)
//   hcw  @ 29408 + wave*2560 + t01*1280: 16 rows x 40 bf16 (packed-b32 writes = 2/bank free)
//
// v12: v11 structure (1024-thr block, 2 blocks/CU target) with the spill fixed.
//      v11 post-mortem: __launch_bounds__(1024,8) capped VGPR+AGPR at 64/wave ->
//      compiler spilled (VGPR_Count 32, +143 MB scratch HBM traffic, dur 48->62us).
//      Fix: (1024,4) budget=128 (v10 compiled to 48 under this), plus b1v[8] moved
//      to LDS broadcasts (-8 loop-carried VGPRs) to coax total alloc <=64 so HW can
//      still co-schedule 2 blocks/CU (32 waves). Worst case >64 -> 1 block/CU = v10
//      occupancy with no scratch.
#define SW1 16384
#define SZC 20480
#define SW2 20512
#define SB2 28704
#define SXT 28832
#define SB1 28896
#define SHC 29408
#define NWAVES 16
#define SMEM_BYTES (29408 + NWAVES * 2560)   // 70368 B -> 2 blocks/CU (140.7 <= 160 KB)

__device__ __forceinline__ f32x8 load8(const float* __restrict__ p) {
    float4 a = *(const float4*)p;
    float4 b = *(const float4*)(p + 4);
    f32x8 v = {a.x, a.y, a.z, a.w, b.x, b.y, b.z, b.w};
    return v;
}

__device__ __forceinline__ int pack2bf(float a, float b) {
    f32x2 v = {a, b};
    bf16x2 p = __builtin_convertvector(v, bf16x2);
    return __builtin_bit_cast(int, p);
}

__global__ __launch_bounds__(1024, 4) void andp_v12(
    const float* __restrict__ x_cur,
    const float* __restrict__ W1,
    const float* __restrict__ b1,
    const float* __restrict__ W2,
    const float* __restrict__ b2,
    const float* __restrict__ Bm,
    const float* __restrict__ Cm,
    const float* __restrict__ x_t,
    float* __restrict__ out)
{
    extern __shared__ char smem[];
    int* sA2i = (int*)smem;
    int* sW1i = (int*)(smem + SW1);
    int* sW2i = (int*)(smem + SW2);
    const int tid = threadIdx.x;

    // ---- stage A2 = Bm + Cm, lane-consecutive chunk order ----
#pragma unroll
    for (int i = 0; i < 4; ++i) {
        int o2 = tid + i * 1024;                // b32 index 0..4095
        int o  = o2 * 2;                        // elem (j even)
        int kk = o >> 9, qp = (o >> 7) & 3, k = (o >> 3) & 15, j = o & 7;
        int n = 2 * kk + (qp >> 1), d = (qp & 1) * 8 + j;
        int src = n * 256 + k * 16 + d;
        float2 bv = *(const float2*)(Bm + src);
        float2 cv = *(const float2*)(Cm + src);
        sA2i[o2] = pack2bf(bv.x + cv.x, bv.y + cv.y);
    }
    // ---- stage W1 frags, lane-consecutive chunk order; + zero chunk ----
    {
        int o2 = tid;                           // b32 index 0..1023 (one per thread)
        int o  = o2 * 2;                        // elem (j even)
        int t = o >> 8, qq = (o >> 7) & 1, cc = (o >> 3) & 15, j = o & 7;
        int src = (t * 16 + cc) * 16 + qq * 8 + j;
        float2 v = *(const float2*)(W1 + src);
        sW1i[o2] = pack2bf(v.x, v.y);
    }
    if (tid < 8) ((int*)(smem + SZC))[tid] = 0;
    // ---- stage W2 in permuted frag order (v9-verified) ----
#pragma unroll
    for (int i = 0; i < 2; ++i) {
        int o2 = tid + i * 1024;                // b32 index 0..2047
        int chunk = o2 >> 8, rem = o2 & 255;
        int ln = rem >> 2, j2 = rem & 3;
        int qq = ln >> 4, cc = ln & 15;
        int t2 = chunk >> 2, s = chunk & 3;
        int src = (t2 * 16 + cc) * 128 + s * 32 + 4 * qq + j2;
        sW2i[o2] = pack2bf(W2[src], W2[src + 16]);
    }
    if (tid < 32) ((float*)(smem + SB2))[tid] = b2[tid];
    if (tid < 16) ((float*)(smem + SXT))[tid] = x_t[tid];
    if (tid < 128) ((float*)(smem + SB1))[tid] = b1[tid];

    const int wave = tid >> 6, lane = tid & 63;
    const int c = lane & 15, q = lane >> 4;
    const int qh = q >> 1;                       // n parity for G3
    const int hh = (q & 1) * 8;                  // d-half this lane owns
    const int c4 = c * 4;

    const char* sW1f = smem + SW1;
    const int w1base = (q < 2) ? ((q * 16 + c) * 16) : (SZC - SW1);
    const int w1step = (q < 2) ? 512 : 0;
    const char* sW2f = smem + SW2 + lane * 16;   // + chunk*1024
    __bf16* hcw0 = (__bf16*)(smem + SHC + wave * 2560);
    __bf16* hcw1 = hcw0 + 640;
    const float* sB2f = (const float*)(smem + SB2);
    const float* sXTf = (const float*)(smem + SXT);
    const float* sB1f = (const float*)(smem + SB1);

    __syncthreads();

    const int blk_row = blockIdx.x * 1024 + wave * 64;
    const f32x4 z4 = {0.f, 0.f, 0.f, 0.f};

#pragma unroll 1
    for (int p = 0; p < 2; ++p) {
        const int r0 = blk_row + p * 32;

        // ---- x from global -> bf16 A-frag only (dif reconstructed at G3) ----
        bf16x8 af[2];
#pragma unroll
        for (int t01 = 0; t01 < 2; ++t01) {
            f32x8 xv = load8(x_cur + (size_t)(r0 + t01 * 16 + c) * 16 + hh);
            af[t01] = __builtin_convertvector(xv, bf16x8);
        }

        // ---- fused G1/G2, t01-interleaved ----
        f32x4 acc2[2][2];
        acc2[0][0] = z4; acc2[0][1] = z4; acc2[1][0] = z4; acc2[1][1] = z4;
#pragma unroll
        for (int s = 0; s < 4; ++s) {
            // b1 broadcast from LDS (was VGPR array b1v[8]): same value for both t01
            float b1a = sB1f[(2 * s) * 16 + c];
            float b1b = sB1f[(2 * s + 1) * 16 + c];
#pragma unroll
            for (int t01 = 0; t01 < 2; ++t01) {
                __bf16* hcw = t01 ? hcw1 : hcw0;
                bf16x8 w1a = *(const bf16x8*)(sW1f + w1base + (2 * s) * w1step);
                bf16x8 w1b = *(const bf16x8*)(sW1f + w1base + (2 * s + 1) * w1step);
                f32x4 a1a = __builtin_amdgcn_mfma_f32_16x16x32_bf16(af[t01], w1a, z4, 0, 0, 0);
                f32x4 a1b = __builtin_amdgcn_mfma_f32_16x16x32_bf16(af[t01], w1b, z4, 0, 0, 0);
#pragma unroll
                for (int r = 0; r < 4; ++r) {
                    float va = fmaxf(a1a[r] + b1a, 0.f);
                    float vb = fmaxf(a1b[r] + b1b, 0.f);
                    *(int*)(hcw + (q * 4 + r) * 40 + 2 * c) = pack2bf(va, vb);
                }
            }
#pragma unroll
            for (int t01 = 0; t01 < 2; ++t01) {
                __bf16* hcw = t01 ? hcw1 : hcw0;
                bf16x8 hb = *(const bf16x8*)(hcw + c * 40 + q * 8);
                bf16x8 w20 = *(const bf16x8*)(sW2f + (0 * 4 + s) * 1024);
                bf16x8 w21 = *(const bf16x8*)(sW2f + (1 * 4 + s) * 1024);
                acc2[t01][0] = __builtin_amdgcn_mfma_f32_16x16x32_bf16(w20, hb, acc2[t01][0], 0, 0, 0);
                acc2[t01][1] = __builtin_amdgcn_mfma_f32_16x16x32_bf16(w21, hb, acc2[t01][1], 0, 0, 0);
            }
        }

        // ---- softmax (no max-sub; b2 from LDS broadcast reads) ----
        int wq[8];
        {
            f32x4 bq0 = *(const f32x4*)(sB2f + q * 4);
            f32x4 bq1 = *(const f32x4*)(sB2f + 16 + q * 4);
#pragma unroll
            for (int t01 = 0; t01 < 2; ++t01) {
                float e[8], sum = 0.f;
#pragma unroll
                for (int r = 0; r < 4; ++r) {
                    e[r]     = __expf(acc2[t01][0][r] + bq0[r]);
                    e[4 + r] = __expf(acc2[t01][1][r] + bq1[r]);
                    sum += e[r] + e[4 + r];
                }
                sum += __shfl_xor(sum, 16, 64);
                sum += __shfl_xor(sum, 32, 64);
                float inv = 1.0f / sum;
                if (t01 == 0) {
#pragma unroll
                    for (int i = 0; i < 8; ++i) wq[i] = pack2bf(e[i] * inv, 0.f);
                } else {
#pragma unroll
                    for (int i = 0; i < 8; ++i) wq[i] |= pack2bf(0.f, e[i] * inv);
                }
            }
        }

        // ---- reconstruct dif from af (bf16 x) + LDS x_target ----
        f32x8 dif[2];
        {
            f32x4 xta = *(const f32x4*)(sXTf + hh);
            f32x4 xtb = *(const f32x4*)(sXTf + hh + 4);
            f32x8 xtv = {xta[0], xta[1], xta[2], xta[3], xtb[0], xtb[1], xtb[2], xtb[3]};
            dif[0] = xtv - __builtin_convertvector(af[0], f32x8);
            dif[1] = xtv - __builtin_convertvector(af[1], f32x8);
        }

        // ---- G3 (v8-verified gate fetch; lane-consecutive A2 chunks) ----
        f32x4 acc3[2];
        acc3[0] = z4; acc3[1] = z4;
#pragma unroll
        for (int kk = 0; kk < 16; ++kk) {
            const int lo = (kk >> 3) * 4 + 2 * (kk & 1);
            const int bpi = c4 + ((kk >> 1) & 3) * 64;
            int bpA = __builtin_amdgcn_ds_bpermute(bpi, wq[lo]);      // n = 2kk
            int bpB = __builtin_amdgcn_ds_bpermute(bpi, wq[lo + 1]);  // n = 2kk+1
            int sel = qh ? bpB : bpA;                                  // n = 2kk+qh
            float w0 = __builtin_bit_cast(float, (unsigned)sel << 16);
            float w1 = __builtin_bit_cast(float, (unsigned)sel & 0xffff0000u);
            bf16x8 a2f = *(const bf16x8*)(smem + kk * 1024 + lane * 16);
            bf16x8 g0 = __builtin_convertvector(dif[0] * w0, bf16x8);
            bf16x8 g1 = __builtin_convertvector(dif[1] * w1, bf16x8);
            acc3[0] = __builtin_amdgcn_mfma_f32_16x16x32_bf16(a2f, g0, acc3[0], 0, 0, 0);
            acc3[1] = __builtin_amdgcn_mfma_f32_16x16x32_bf16(a2f, g1, acc3[1], 0, 0, 0);
        }

        // ---- store: D[m=k_out=q*4+r][n=row=c] -> float4 per tile ----
#pragma unroll
        for (int t01 = 0; t01 < 2; ++t01) {
            float4 st = make_float4(acc3[t01][0], acc3[t01][1], acc3[t01][2], acc3[t01][3]);
            *(float4*)(out + (size_t)(r0 + t01 * 16 + c) * 16 + q * 4) = st;
        }
    }
}

extern "C" void kernel_launch(void* const* d_in, const int* in_sizes, int n_in,
                              void* d_out, int out_size, void* d_ws, size_t ws_size,
                              hipStream_t stream) {
    const float* x_cur = (const float*)d_in[0];
    const float* W1    = (const float*)d_in[1];
    const float* b1    = (const float*)d_in[2];
    const float* W2    = (const float*)d_in[3];
    const float* b2    = (const float*)d_in[4];
    const float* Bm    = (const float*)d_in[5];
    const float* Cm    = (const float*)d_in[6];
    const float* x_t   = (const float*)d_in[7];
    float* out = (float*)d_out;

    // >64KB dynamic LDS needs explicit opt-in (one-time; not a stream op, graph-safe)
    static bool attr_set = false;
    if (!attr_set) {
        (void)hipFuncSetAttribute((const void*)andp_v12,
                                  hipFuncAttributeMaxDynamicSharedMemorySize,
                                  SMEM_BYTES);
        attr_set = true;
    }

    const int blocks = BATCH / 1024;   // 512 blocks x 1024 rows
    andp_v12<<<blocks, 1024, SMEM_BYTES, stream>>>(
        x_cur, W1, b1, W2, b2, Bm, Cm, x_t, out);
}

// Round 4
// 118.414 us; speedup vs baseline: 1.2049x; 1.0823x over previous
//
#include <hip/hip_runtime.h>

#define BATCH 524288

typedef __bf16 bf16x8 __attribute__((ext_vector_type(8)));
typedef __bf16 bf16x2 __attribute__((ext_vector_type(2)));
typedef float f32x4 __attribute__((ext_vector_type(4)));
typedef float f32x8 __attribute__((ext_vector_type(8)));
typedef float f32x2 __attribute__((ext_vector_type(2)));

// LDS layout (all fragment reads are lane-consecutive 16B chunks = conflict-free):
//   sA2  @     0: 16384 B  A2, chunk(kk, lane)=kk*1024+lane*16; lane(c,q) elems j ->
//                          A[n=2kk+(q>>1)][k_out=c][d=(q&1)*8+j]
//   sW1f @ 16384:  4096 B  W1 frags, chunk(t, q*16+c) for q<2; +32 B zero chunk @ 20480
//   sW2f @ 20512:  8192 B  W2 permuted frags (v9-verified), chunk(t2*4+s)*1024 + lane*16
//   sB2  @ 28704:   128 B  b2 f32 (broadcast float4 reads)
//   sXT  @ 28832:    64 B  x_target f32
//   sB1  @ 28896:   512 B  b1 f32 (broadcast reads, replaces b1v[8] VGPR array)
//   hcw  @ 29408 + wave*2560 + t01*1280: 16 rows x 40 bf16 (packed-b32 writes = 2/bank free)
//
// v13: 512-thread blocks, 3 blocks/CU (24 waves/CU = 6 waves/SIMD, 1.5x v10).
//      v11/v12 post-mortem: hipcc's __launch_bounds__ 2nd arg behaved as CUDA
//      min-BLOCKS/CU: (1024,4) -> 16 waves/SIMD req -> clamp 8 -> 64-VGPR budget ->
//      spill (VGPR_Count=64 + 13MB scratch writes). Live set ~70 regs can't fit 8
//      waves/SIMD, but fits 6 (budget 512/6=85). 512-thr: LDS 49888 B -> 3 blocks/CU
//      by LDS (149.7/160 KB), launch_bounds(512,3) -> budget 85 -> no spill.
#define SW1 16384
#define SZC 20480
#define SW2 20512
#define SB2 28704
#define SXT 28832
#define SB1 28896
#define SHC 29408
#define NWAVES 8
#define SMEM_BYTES (29408 + NWAVES * 2560)   // 49888 B -> 3 blocks/CU

__device__ __forceinline__ f32x8 load8(const float* __restrict__ p) {
    float4 a = *(const float4*)p;
    float4 b = *(const float4*)(p + 4);
    f32x8 v = {a.x, a.y, a.z, a.w, b.x, b.y, b.z, b.w};
    return v;
}

__device__ __forceinline__ int pack2bf(float a, float b) {
    f32x2 v = {a, b};
    bf16x2 p = __builtin_convertvector(v, bf16x2);
    return __builtin_bit_cast(int, p);
}

__global__ __launch_bounds__(512, 3) void andp_v13(
    const float* __restrict__ x_cur,
    const float* __restrict__ W1,
    const float* __restrict__ b1,
    const float* __restrict__ W2,
    const float* __restrict__ b2,
    const float* __restrict__ Bm,
    const float* __restrict__ Cm,
    const float* __restrict__ x_t,
    float* __restrict__ out)
{
    extern __shared__ char smem[];
    int* sA2i = (int*)smem;
    int* sW1i = (int*)(smem + SW1);
    int* sW2i = (int*)(smem + SW2);
    const int tid = threadIdx.x;

    // ---- stage A2 = Bm + Cm, lane-consecutive chunk order ----
#pragma unroll
    for (int i = 0; i < 8; ++i) {
        int o2 = tid + i * 512;                 // b32 index 0..4095
        int o  = o2 * 2;                        // elem (j even)
        int kk = o >> 9, qp = (o >> 7) & 3, k = (o >> 3) & 15, j = o & 7;
        int n = 2 * kk + (qp >> 1), d = (qp & 1) * 8 + j;
        int src = n * 256 + k * 16 + d;
        float2 bv = *(const float2*)(Bm + src);
        float2 cv = *(const float2*)(Cm + src);
        sA2i[o2] = pack2bf(bv.x + cv.x, bv.y + cv.y);
    }
    // ---- stage W1 frags, lane-consecutive chunk order; + zero chunk ----
#pragma unroll
    for (int i = 0; i < 2; ++i) {
        int o2 = tid + i * 512;                 // b32 index 0..1023
        int o  = o2 * 2;                        // elem (j even)
        int t = o >> 8, qq = (o >> 7) & 1, cc = (o >> 3) & 15, j = o & 7;
        int src = (t * 16 + cc) * 16 + qq * 8 + j;
        float2 v = *(const float2*)(W1 + src);
        sW1i[o2] = pack2bf(v.x, v.y);
    }
    if (tid < 8) ((int*)(smem + SZC))[tid] = 0;
    // ---- stage W2 in permuted frag order (v9-verified) ----
#pragma unroll
    for (int i = 0; i < 4; ++i) {
        int o2 = tid + i * 512;                 // b32 index 0..2047
        int chunk = o2 >> 8, rem = o2 & 255;
        int ln = rem >> 2, j2 = rem & 3;
        int qq = ln >> 4, cc = ln & 15;
        int t2 = chunk >> 2, s = chunk & 3;
        int src = (t2 * 16 + cc) * 128 + s * 32 + 4 * qq + j2;
        sW2i[o2] = pack2bf(W2[src], W2[src + 16]);
    }
    if (tid < 32) ((float*)(smem + SB2))[tid] = b2[tid];
    if (tid < 16) ((float*)(smem + SXT))[tid] = x_t[tid];
    if (tid < 128) ((float*)(smem + SB1))[tid] = b1[tid];

    const int wave = tid >> 6, lane = tid & 63;
    const int c = lane & 15, q = lane >> 4;
    const int qh = q >> 1;                       // n parity for G3
    const int hh = (q & 1) * 8;                  // d-half this lane owns
    const int c4 = c * 4;

    const char* sW1f = smem + SW1;
    const int w1base = (q < 2) ? ((q * 16 + c) * 16) : (SZC - SW1);
    const int w1step = (q < 2) ? 512 : 0;
    const char* sW2f = smem + SW2 + lane * 16;   // + chunk*1024
    __bf16* hcw0 = (__bf16*)(smem + SHC + wave * 2560);
    __bf16* hcw1 = hcw0 + 640;
    const float* sB2f = (const float*)(smem + SB2);
    const float* sXTf = (const float*)(smem + SXT);
    const float* sB1f = (const float*)(smem + SB1);

    __syncthreads();

    const int blk_row = blockIdx.x * 512 + wave * 64;
    const f32x4 z4 = {0.f, 0.f, 0.f, 0.f};

#pragma unroll 1
    for (int p = 0; p < 2; ++p) {
        const int r0 = blk_row + p * 32;

        // ---- x from global -> bf16 A-frag only (dif reconstructed at G3) ----
        bf16x8 af[2];
#pragma unroll
        for (int t01 = 0; t01 < 2; ++t01) {
            f32x8 xv = load8(x_cur + (size_t)(r0 + t01 * 16 + c) * 16 + hh);
            af[t01] = __builtin_convertvector(xv, bf16x8);
        }

        // ---- fused G1/G2, t01-interleaved ----
        f32x4 acc2[2][2];
        acc2[0][0] = z4; acc2[0][1] = z4; acc2[1][0] = z4; acc2[1][1] = z4;
#pragma unroll
        for (int s = 0; s < 4; ++s) {
            // b1 broadcast from LDS (was VGPR array b1v[8]): same value for both t01
            float b1a = sB1f[(2 * s) * 16 + c];
            float b1b = sB1f[(2 * s + 1) * 16 + c];
#pragma unroll
            for (int t01 = 0; t01 < 2; ++t01) {
                __bf16* hcw = t01 ? hcw1 : hcw0;
                bf16x8 w1a = *(const bf16x8*)(sW1f + w1base + (2 * s) * w1step);
                bf16x8 w1b = *(const bf16x8*)(sW1f + w1base + (2 * s + 1) * w1step);
                f32x4 a1a = __builtin_amdgcn_mfma_f32_16x16x32_bf16(af[t01], w1a, z4, 0, 0, 0);
                f32x4 a1b = __builtin_amdgcn_mfma_f32_16x16x32_bf16(af[t01], w1b, z4, 0, 0, 0);
#pragma unroll
                for (int r = 0; r < 4; ++r) {
                    float va = fmaxf(a1a[r] + b1a, 0.f);
                    float vb = fmaxf(a1b[r] + b1b, 0.f);
                    *(int*)(hcw + (q * 4 + r) * 40 + 2 * c) = pack2bf(va, vb);
                }
            }
#pragma unroll
            for (int t01 = 0; t01 < 2; ++t01) {
                __bf16* hcw = t01 ? hcw1 : hcw0;
                bf16x8 hb = *(const bf16x8*)(hcw + c * 40 + q * 8);
                bf16x8 w20 = *(const bf16x8*)(sW2f + (0 * 4 + s) * 1024);
                bf16x8 w21 = *(const bf16x8*)(sW2f + (1 * 4 + s) * 1024);
                acc2[t01][0] = __builtin_amdgcn_mfma_f32_16x16x32_bf16(w20, hb, acc2[t01][0], 0, 0, 0);
                acc2[t01][1] = __builtin_amdgcn_mfma_f32_16x16x32_bf16(w21, hb, acc2[t01][1], 0, 0, 0);
            }
        }

        // ---- softmax (no max-sub; b2 from LDS broadcast reads) ----
        int wq[8];
        {
            f32x4 bq0 = *(const f32x4*)(sB2f + q * 4);
            f32x4 bq1 = *(const f32x4*)(sB2f + 16 + q * 4);
#pragma unroll
            for (int t01 = 0; t01 < 2; ++t01) {
                float e[8], sum = 0.f;
#pragma unroll
                for (int r = 0; r < 4; ++r) {
                    e[r]     = __expf(acc2[t01][0][r] + bq0[r]);
                    e[4 + r] = __expf(acc2[t01][1][r] + bq1[r]);
                    sum += e[r] + e[4 + r];
                }
                sum += __shfl_xor(sum, 16, 64);
                sum += __shfl_xor(sum, 32, 64);
                float inv = 1.0f / sum;
                if (t01 == 0) {
#pragma unroll
                    for (int i = 0; i < 8; ++i) wq[i] = pack2bf(e[i] * inv, 0.f);
                } else {
#pragma unroll
                    for (int i = 0; i < 8; ++i) wq[i] |= pack2bf(0.f, e[i] * inv);
                }
            }
        }

        // ---- reconstruct dif from af (bf16 x) + LDS x_target ----
        f32x8 dif[2];
        {
            f32x4 xta = *(const f32x4*)(sXTf + hh);
            f32x4 xtb = *(const f32x4*)(sXTf + hh + 4);
            f32x8 xtv = {xta[0], xta[1], xta[2], xta[3], xtb[0], xtb[1], xtb[2], xtb[3]};
            dif[0] = xtv - __builtin_convertvector(af[0], f32x8);
            dif[1] = xtv - __builtin_convertvector(af[1], f32x8);
        }

        // ---- G3 (v8-verified gate fetch; lane-consecutive A2 chunks) ----
        f32x4 acc3[2];
        acc3[0] = z4; acc3[1] = z4;
#pragma unroll
        for (int kk = 0; kk < 16; ++kk) {
            const int lo = (kk >> 3) * 4 + 2 * (kk & 1);
            const int bpi = c4 + ((kk >> 1) & 3) * 64;
            int bpA = __builtin_amdgcn_ds_bpermute(bpi, wq[lo]);      // n = 2kk
            int bpB = __builtin_amdgcn_ds_bpermute(bpi, wq[lo + 1]);  // n = 2kk+1
            int sel = qh ? bpB : bpA;                                  // n = 2kk+qh
            float w0 = __builtin_bit_cast(float, (unsigned)sel << 16);
            float w1 = __builtin_bit_cast(float, (unsigned)sel & 0xffff0000u);
            bf16x8 a2f = *(const bf16x8*)(smem + kk * 1024 + lane * 16);
            bf16x8 g0 = __builtin_convertvector(dif[0] * w0, bf16x8);
            bf16x8 g1 = __builtin_convertvector(dif[1] * w1, bf16x8);
            acc3[0] = __builtin_amdgcn_mfma_f32_16x16x32_bf16(a2f, g0, acc3[0], 0, 0, 0);
            acc3[1] = __builtin_amdgcn_mfma_f32_16x16x32_bf16(a2f, g1, acc3[1], 0, 0, 0);
        }

        // ---- store: D[m=k_out=q*4+r][n=row=c] -> float4 per tile ----
#pragma unroll
        for (int t01 = 0; t01 < 2; ++t01) {
            float4 st = make_float4(acc3[t01][0], acc3[t01][1], acc3[t01][2], acc3[t01][3]);
            *(float4*)(out + (size_t)(r0 + t01 * 16 + c) * 16 + q * 4) = st;
        }
    }
}

extern "C" void kernel_launch(void* const* d_in, const int* in_sizes, int n_in,
                              void* d_out, int out_size, void* d_ws, size_t ws_size,
                              hipStream_t stream) {
    const float* x_cur = (const float*)d_in[0];
    const float* W1    = (const float*)d_in[1];
    const float* b1    = (const float*)d_in[2];
    const float* W2    = (const float*)d_in[3];
    const float* b2    = (const float*)d_in[4];
    const float* Bm    = (const float*)d_in[5];
    const float* Cm    = (const float*)d_in[6];
    const float* x_t   = (const float*)d_in[7];
    float* out = (float*)d_out;

    const int blocks = BATCH / 512;   // 1024 blocks x 512 rows, 3 blocks/CU resident
    andp_v13<<<blocks, 512, SMEM_BYTES, stream>>>(
        x_cur, W1, b1, W2, b2, Bm, Cm, x_t, out);
}

// Round 6
// 116.761 us; speedup vs baseline: 1.2220x; 1.0142x over previous
//
#include <hip/hip_runtime.h>

#define BATCH 524288

typedef __bf16 bf16x8 __attribute__((ext_vector_type(8)));
typedef __bf16 bf16x2 __attribute__((ext_vector_type(2)));
typedef float f32x4 __attribute__((ext_vector_type(4)));
typedef float f32x8 __attribute__((ext_vector_type(8)));
typedef float f32x2 __attribute__((ext_vector_type(2)));
typedef int   i32x4 __attribute__((ext_vector_type(4)));

// LDS layout (all fragment reads are lane-consecutive 16B chunks = conflict-free):
//   sA2  @     0: 16384 B  A2, chunk(kk, lane)=kk*1024+lane*16
//   sW1f @ 16384:  4096 B  W1 frags; +32 B zero chunk @ 20480
//   sW2f @ 20512:  8192 B  W2 permuted frags (v9-verified)
//   sB2  @ 28704:   128 B  b2 f32 (f32x4 broadcast reads, seeds G2 C-operand)
//   sXT  @ 28832:    64 B  x_target f32
//   sB1r @ 28896:  2048 B  b1 replicated x4 (f32x4 splat reads, seeds G1 C-operand)
//   hcw  @ 30944 + wave*2560 + t01*1280: 16 rows x 40 bf16
//
// v14: VALU diet (v13 post-mortem: 20us of VALU issue vs 6us MFMA; occupancy raises
//      exhausted at -8%). (1) G1 bias -> MFMA C-seed via x4-replicated b1 LDS table
//      (-64 v_add/p); (2) G2 bias -> C-seed from bq0/bq1 (-16 v_add/p, hoisted);
//      (3) G3 dif*w as f32x2 ops to coax v_pk_mul_f32 (-128 slots if formed);
//      (4) next-p x prefetch after s-loop (hides HBM latency under softmax+G3).
//      Keeps 512-thr / (512,3) / 3 blocks/CU (VGPR budget 85, v13 had 48, no spill).
#define SW1 16384
#define SZC 20480
#define SW2 20512
#define SB2 28704
#define SXT 28832
#define SB1 28896
#define SHC 30944
#define NWAVES 8
#define SMEM_BYTES (30944 + NWAVES * 2560)   // 51424 B -> 3 blocks/CU (154.3/160 KB)

__device__ __forceinline__ f32x8 load8(const float* __restrict__ p) {
    float4 a = *(const float4*)p;
    float4 b = *(const float4*)(p + 4);
    f32x8 v = {a.x, a.y, a.z, a.w, b.x, b.y, b.z, b.w};
    return v;
}

__device__ __forceinline__ int pack2bf(float a, float b) {
    f32x2 v = {a, b};
    bf16x2 p = __builtin_convertvector(v, bf16x2);
    return __builtin_bit_cast(int, p);
}

__global__ __launch_bounds__(512, 3) void andp_v14(
    const float* __restrict__ x_cur,
    const float* __restrict__ W1,
    const float* __restrict__ b1,
    const float* __restrict__ W2,
    const float* __restrict__ b2,
    const float* __restrict__ Bm,
    const float* __restrict__ Cm,
    const float* __restrict__ x_t,
    float* __restrict__ out)
{
    extern __shared__ char smem[];
    int* sA2i = (int*)smem;
    int* sW1i = (int*)(smem + SW1);
    int* sW2i = (int*)(smem + SW2);
    const int tid = threadIdx.x;

    // ---- stage A2 = Bm + Cm, lane-consecutive chunk order ----
#pragma unroll
    for (int i = 0; i < 8; ++i) {
        int o2 = tid + i * 512;                 // b32 index 0..4095
        int o  = o2 * 2;                        // elem (j even)
        int kk = o >> 9, qp = (o >> 7) & 3, k = (o >> 3) & 15, j = o & 7;
        int n = 2 * kk + (qp >> 1), d = (qp & 1) * 8 + j;
        int src = n * 256 + k * 16 + d;
        float2 bv = *(const float2*)(Bm + src);
        float2 cv = *(const float2*)(Cm + src);
        sA2i[o2] = pack2bf(bv.x + cv.x, bv.y + cv.y);
    }
    // ---- stage W1 frags, lane-consecutive chunk order; + zero chunk ----
#pragma unroll
    for (int i = 0; i < 2; ++i) {
        int o2 = tid + i * 512;                 // b32 index 0..1023
        int o  = o2 * 2;                        // elem (j even)
        int t = o >> 8, qq = (o >> 7) & 1, cc = (o >> 3) & 15, j = o & 7;
        int src = (t * 16 + cc) * 16 + qq * 8 + j;
        float2 v = *(const float2*)(W1 + src);
        sW1i[o2] = pack2bf(v.x, v.y);
    }
    if (tid < 8) ((int*)(smem + SZC))[tid] = 0;
    // ---- stage W2 in permuted frag order (v9-verified) ----
#pragma unroll
    for (int i = 0; i < 4; ++i) {
        int o2 = tid + i * 512;                 // b32 index 0..2047
        int chunk = o2 >> 8, rem = o2 & 255;
        int ln = rem >> 2, j2 = rem & 3;
        int qq = ln >> 4, cc = ln & 15;
        int t2 = chunk >> 2, s = chunk & 3;
        int src = (t2 * 16 + cc) * 128 + s * 32 + 4 * qq + j2;
        sW2i[o2] = pack2bf(W2[src], W2[src + 16]);
    }
    if (tid < 32) ((float*)(smem + SB2))[tid] = b2[tid];
    if (tid < 16) ((float*)(smem + SXT))[tid] = x_t[tid];
    // b1 replicated x4 so a single ds_read_b128 yields splat(b1[h]) for the C-seed
    if (tid < 128) {
        float v = b1[tid];
        ((float4*)(smem + SB1))[tid] = make_float4(v, v, v, v);
    }

    const int wave = tid >> 6, lane = tid & 63;
    const int c = lane & 15, q = lane >> 4;
    const int qh = q >> 1;                       // n parity for G3
    const int hh = (q & 1) * 8;                  // d-half this lane owns
    const int c4 = c * 4;

    const char* sW1f = smem + SW1;
    const int w1base = (q < 2) ? ((q * 16 + c) * 16) : (SZC - SW1);
    const int w1step = (q < 2) ? 512 : 0;
    const char* sW2f = smem + SW2 + lane * 16;   // + chunk*1024
    __bf16* hcw0 = (__bf16*)(smem + SHC + wave * 2560);
    __bf16* hcw1 = hcw0 + 640;
    const float* sB2f = (const float*)(smem + SB2);
    const float* sXTf = (const float*)(smem + SXT);
    const float* sB1r = (const float*)(smem + SB1);

    __syncthreads();

    const int blk_row = blockIdx.x * 512 + wave * 64;
    const f32x4 z4 = {0.f, 0.f, 0.f, 0.f};

    // p-invariant G2 bias seeds (layout matches D: reg r <-> n = half*16 + q*4+r)
    const f32x4 bq0 = *(const f32x4*)(sB2f + q * 4);
    const f32x4 bq1 = *(const f32x4*)(sB2f + 16 + q * 4);

    // ---- p=0 x load (prefetched inside loop thereafter) ----
    bf16x8 af[2];
#pragma unroll
    for (int t01 = 0; t01 < 2; ++t01) {
        f32x8 xv = load8(x_cur + (size_t)(blk_row + t01 * 16 + c) * 16 + hh);
        af[t01] = __builtin_convertvector(xv, bf16x8);
    }

#pragma unroll 1
    for (int p = 0; p < 2; ++p) {
        const int r0 = blk_row + p * 32;

        // ---- fused G1/G2, t01-interleaved; bias enters via MFMA C-operand ----
        f32x4 acc2[2][2];
        acc2[0][0] = bq0; acc2[0][1] = bq1; acc2[1][0] = bq0; acc2[1][1] = bq1;
#pragma unroll
        for (int s = 0; s < 4; ++s) {
            // splat(b1[h]) C-seeds: h = (2s)*16+c and (2s+1)*16+c (t01-invariant)
            f32x4 cba = *(const f32x4*)(sB1r + ((2 * s) * 16 + c) * 4);
            f32x4 cbb = *(const f32x4*)(sB1r + ((2 * s + 1) * 16 + c) * 4);
#pragma unroll
            for (int t01 = 0; t01 < 2; ++t01) {
                __bf16* hcw = t01 ? hcw1 : hcw0;
                bf16x8 w1a = *(const bf16x8*)(sW1f + w1base + (2 * s) * w1step);
                bf16x8 w1b = *(const bf16x8*)(sW1f + w1base + (2 * s + 1) * w1step);
                f32x4 a1a = __builtin_amdgcn_mfma_f32_16x16x32_bf16(af[t01], w1a, cba, 0, 0, 0);
                f32x4 a1b = __builtin_amdgcn_mfma_f32_16x16x32_bf16(af[t01], w1b, cbb, 0, 0, 0);
#pragma unroll
                for (int r = 0; r < 4; ++r) {
                    float va = fmaxf(a1a[r], 0.f);
                    float vb = fmaxf(a1b[r], 0.f);
                    *(int*)(hcw + (q * 4 + r) * 40 + 2 * c) = pack2bf(va, vb);
                }
            }
#pragma unroll
            for (int t01 = 0; t01 < 2; ++t01) {
                __bf16* hcw = t01 ? hcw1 : hcw0;
                bf16x8 hb = *(const bf16x8*)(hcw + c * 40 + q * 8);
                bf16x8 w20 = *(const bf16x8*)(sW2f + (0 * 4 + s) * 1024);
                bf16x8 w21 = *(const bf16x8*)(sW2f + (1 * 4 + s) * 1024);
                acc2[t01][0] = __builtin_amdgcn_mfma_f32_16x16x32_bf16(w20, hb, acc2[t01][0], 0, 0, 0);
                acc2[t01][1] = __builtin_amdgcn_mfma_f32_16x16x32_bf16(w21, hb, acc2[t01][1], 0, 0, 0);
            }
        }

        // ---- prefetch next-p x (issued here so HBM latency hides under SM+G3) ----
        bf16x8 afn0 = af[0], afn1 = af[1];
        if (p == 0) {
            f32x8 xv0 = load8(x_cur + (size_t)(blk_row + 32 + c) * 16 + hh);
            f32x8 xv1 = load8(x_cur + (size_t)(blk_row + 48 + c) * 16 + hh);
            afn0 = __builtin_convertvector(xv0, bf16x8);
            afn1 = __builtin_convertvector(xv1, bf16x8);
        }

        // ---- softmax (bias already inside acc2; no max-sub) ----
        int wq[8];
        {
#pragma unroll
            for (int t01 = 0; t01 < 2; ++t01) {
                float e[8], sum = 0.f;
#pragma unroll
                for (int r = 0; r < 4; ++r) {
                    e[r]     = __expf(acc2[t01][0][r]);
                    e[4 + r] = __expf(acc2[t01][1][r]);
                    sum += e[r] + e[4 + r];
                }
                sum += __shfl_xor(sum, 16, 64);
                sum += __shfl_xor(sum, 32, 64);
                float inv = 1.0f / sum;
                if (t01 == 0) {
#pragma unroll
                    for (int i = 0; i < 8; ++i) wq[i] = pack2bf(e[i] * inv, 0.f);
                } else {
#pragma unroll
                    for (int i = 0; i < 8; ++i) wq[i] |= pack2bf(0.f, e[i] * inv);
                }
            }
        }

        // ---- reconstruct dif from af (bf16 x) + LDS x_target ----
        f32x8 dif[2];
        {
            f32x4 xta = *(const f32x4*)(sXTf + hh);
            f32x4 xtb = *(const f32x4*)(sXTf + hh + 4);
            f32x8 xtv = {xta[0], xta[1], xta[2], xta[3], xtb[0], xtb[1], xtb[2], xtb[3]};
            dif[0] = xtv - __builtin_convertvector(af[0], f32x8);
            dif[1] = xtv - __builtin_convertvector(af[1], f32x8);
        }

        // ---- G3 (v8-verified gate fetch; f32x2-structured scaling for pk_mul) ----
        f32x4 acc3[2];
        acc3[0] = z4; acc3[1] = z4;
#pragma unroll
        for (int kk = 0; kk < 16; ++kk) {
            const int lo = (kk >> 3) * 4 + 2 * (kk & 1);
            const int bpi = c4 + ((kk >> 1) & 3) * 64;
            int bpA = __builtin_amdgcn_ds_bpermute(bpi, wq[lo]);      // n = 2kk
            int bpB = __builtin_amdgcn_ds_bpermute(bpi, wq[lo + 1]);  // n = 2kk+1
            int sel = qh ? bpB : bpA;                                  // n = 2kk+qh
            float w0 = __builtin_bit_cast(float, (unsigned)sel << 16);
            float w1 = __builtin_bit_cast(float, (unsigned)sel & 0xffff0000u);
            f32x2 w0p = {w0, w0}, w1p = {w1, w1};
            i32x4 g0i, g1i;
#pragma unroll
            for (int jj = 0; jj < 4; ++jj) {
                f32x2 d0 = {dif[0][2 * jj], dif[0][2 * jj + 1]};
                f32x2 d1 = {dif[1][2 * jj], dif[1][2 * jj + 1]};
                f32x2 p0 = d0 * w0p;
                f32x2 p1 = d1 * w1p;
                g0i[jj] = pack2bf(p0[0], p0[1]);
                g1i[jj] = pack2bf(p1[0], p1[1]);
            }
            bf16x8 a2f = *(const bf16x8*)(smem + kk * 1024 + lane * 16);
            bf16x8 g0 = __builtin_bit_cast(bf16x8, g0i);
            bf16x8 g1 = __builtin_bit_cast(bf16x8, g1i);
            acc3[0] = __builtin_amdgcn_mfma_f32_16x16x32_bf16(a2f, g0, acc3[0], 0, 0, 0);
            acc3[1] = __builtin_amdgcn_mfma_f32_16x16x32_bf16(a2f, g1, acc3[1], 0, 0, 0);
        }

        // ---- store: D[m=k_out=q*4+r][n=row=c] -> float4 per tile ----
#pragma unroll
        for (int t01 = 0; t01 < 2; ++t01) {
            float4 st = make_float4(acc3[t01][0], acc3[t01][1], acc3[t01][2], acc3[t01][3]);
            *(float4*)(out + (size_t)(r0 + t01 * 16 + c) * 16 + q * 4) = st;
        }

        af[0] = afn0;
        af[1] = afn1;
    }
}

extern "C" void kernel_launch(void* const* d_in, const int* in_sizes, int n_in,
                              void* d_out, int out_size, void* d_ws, size_t ws_size,
                              hipStream_t stream) {
    const float* x_cur = (const float*)d_in[0];
    const float* W1    = (const float*)d_in[1];
    const float* b1    = (const float*)d_in[2];
    const float* W2    = (const float*)d_in[3];
    const float* b2    = (const float*)d_in[4];
    const float* Bm    = (const float*)d_in[5];
    const float* Cm    = (const float*)d_in[6];
    const float* x_t   = (const float*)d_in[7];
    float* out = (float*)d_out;

    const int blocks = BATCH / 512;   // 1024 blocks x 512 rows, 3 blocks/CU resident
    andp_v14<<<blocks, 512, SMEM_BYTES, stream>>>(
        x_cur, W1, b1, W2, b2, Bm, Cm, x_t, out);
}